// Round 2
// baseline (154.666 us; speedup 1.0000x reference)
//
#include <hip/hip_runtime.h>

#define BLK 256
#define CAP 4096   // max group size held in LDS (16 KB); n>CAP falls back to global-memory path

// ---------- block-wide reductions (256 threads = 4 waves of 64) ----------

__device__ __forceinline__ float block_max(float v, float* redf, int tid) {
#pragma unroll
  for (int o = 32; o; o >>= 1) v = fmaxf(v, __shfl_down(v, o));
  __syncthreads();                       // protect redf from previous readers
  if ((tid & 63) == 0) redf[tid >> 6] = v;
  __syncthreads();
  return fmaxf(fmaxf(redf[0], redf[1]), fmaxf(redf[2], redf[3]));
}

__device__ __forceinline__ void block_sum_cnt(float& s, int& c, float* redf, int* redi, int tid) {
#pragma unroll
  for (int o = 32; o; o >>= 1) { s += __shfl_down(s, o); c += __shfl_down(c, o); }
  __syncthreads();
  if ((tid & 63) == 0) { redf[tid >> 6] = s; redi[tid >> 6] = c; }
  __syncthreads();
  s = redf[0] + redf[1] + redf[2] + redf[3];
  c = redi[0] + redi[1] + redi[2] + redi[3];
}

// ---------- block-cooperative 257-ary lower_bound over sorted int32 keys ----------
// Returns smallest i in [0,N] with batch[i] >= target. ~3-4 probe rounds for N=8.4M.
__device__ __forceinline__ int block_lower_bound(const int* __restrict__ batch, int N,
                                                 int target, int tid, int* s_cnt) {
  int lo = 0, hi = N;                    // answer invariant: in [lo, hi]
  while (hi > lo) {
    long long span = hi - lo;            // span*257 can exceed 2^31 -> 64-bit product
    int m = lo + (int)((span * (long long)(tid + 1)) / (BLK + 1));  // m in [lo, hi-1]
    int flag = (batch[m] < target) ? 1 : 0;                          // monotone 1..1 0..0 across tid
    unsigned long long bal = __ballot(flag);
    __syncthreads();                     // previous round's s_cnt read is done
    if (tid == 0) *s_cnt = 0;
    __syncthreads();
    if ((tid & 63) == 0) atomicAdd(s_cnt, __popcll(bal));
    __syncthreads();
    int c = *s_cnt;                      // # probes strictly below target
    int nlo = lo, nhi = hi;
    if (c > 0)   nlo = lo + (int)((span * (long long)c) / (BLK + 1)) + 1;      // m_{c-1}+1
    if (c < BLK) nhi = lo + (int)((span * (long long)(c + 1)) / (BLK + 1));    // m_c
    lo = nlo; hi = nhi;                  // strict shrink every round; terminates at lo==hi
  }
  return lo;
}

// ---------- main kernel: one block per group, Michelot simplex projection ----------

extern "C" __global__ void __launch_bounds__(BLK)
sparsemax_groups(const float* __restrict__ x, const int* __restrict__ batch,
                 const int* __restrict__ pB, float* __restrict__ out, int N) {
  __shared__ float xs[CAP];
  __shared__ float redf[4];
  __shared__ int   redi[4];
  __shared__ int   s_cnt;
  const int tid = threadIdx.x;
  const int B = *pB;                     // num_groups scalar (int32 on device)

  for (int g = blockIdx.x; g < B; g += gridDim.x) {
    const int s = block_lower_bound(batch, N, g,     tid, &s_cnt);
    const int e = block_lower_bound(batch, N, g + 1, tid, &s_cnt);
    const int n = e - s;
    if (n <= 0) continue;                // empty group: no output elements exist

    if (n <= CAP) {
      // Pass 1: load group into LDS, fold max
      float m = -INFINITY;
      for (int i = tid; i < n; i += BLK) { float v = x[s + i]; xs[i] = v; m = fmaxf(m, v); }
      const float gmax = block_max(m, redf, tid);

      // Pass 2: shift by gmax in LDS, initial sum
      float ls = 0.0f; int lc = 0;
      for (int i = tid; i < n; i += BLK) { float v = xs[i] - gmax; xs[i] = v; ls += v; }
      block_sum_cnt(ls, lc, redf, redi, tid);

      float tau = (ls - 1.0f) / (float)n;
      int cnt = n;
      // Michelot iterations: support strictly shrinks; ~9-12 iters for Gaussian n=2048
      for (int it = 0; it < 64; ++it) {
        float bs = 0.0f; int bc = 0;
        for (int i = tid; i < n; i += BLK) { float v = xs[i]; if (v > tau) { bs += v; bc++; } }
        block_sum_cnt(bs, bc, redf, redi, tid);
        if (bc == cnt || bc == 0) break; // fixed point (bc>=1 always: max elem 0 > tau < 0)
        tau = (bs - 1.0f) / (float)bc;
        cnt = bc;
      }

      for (int i = tid; i < n; i += BLK) {
        float v = xs[i] - tau;
        out[s + i] = v > 0.0f ? v : 0.0f;
      }
    } else {
      // Fallback for oversized groups: identical algorithm, re-reads x from global
      float m = -INFINITY;
      for (int i = tid; i < n; i += BLK) m = fmaxf(m, x[s + i]);
      const float gmax = block_max(m, redf, tid);

      float ls = 0.0f; int lc = 0;
      for (int i = tid; i < n; i += BLK) ls += x[s + i] - gmax;
      block_sum_cnt(ls, lc, redf, redi, tid);

      float tau = (ls - 1.0f) / (float)n;
      int cnt = n;
      for (int it = 0; it < 64; ++it) {
        float bs = 0.0f; int bc = 0;
        for (int i = tid; i < n; i += BLK) { float v = x[s + i] - gmax; if (v > tau) { bs += v; bc++; } }
        block_sum_cnt(bs, bc, redf, redi, tid);
        if (bc == cnt || bc == 0) break;
        tau = (bs - 1.0f) / (float)bc;
        cnt = bc;
      }

      for (int i = tid; i < n; i += BLK) {
        float v = x[s + i] - gmax - tau;
        out[s + i] = v > 0.0f ? v : 0.0f;
      }
    }
  }
}

extern "C" void kernel_launch(void* const* d_in, const int* in_sizes, int n_in,
                              void* d_out, int out_size, void* d_ws, size_t ws_size,
                              hipStream_t stream) {
  const float* x     = (const float*)d_in[0];
  const int*   batch = (const int*)d_in[1];   // int32 on device (JAX x64 disabled downcasts int64)
  const int*   pB    = (const int*)d_in[2];   // num_groups scalar (device)
  float*       out   = (float*)d_out;
  const int N = in_sizes[0];

  // grid = 4096 matches B in setup_inputs; kernel grid-strides over groups if B differs
  sparsemax_groups<<<dim3(4096), dim3(BLK), 0, stream>>>(x, batch, pB, out, N);
}

// Round 3
// 129.327 us; speedup vs baseline: 1.1959x; 1.1959x over previous
//
#include <hip/hip_runtime.h>

#define BLK 256
#define EPT 16                 // elements per thread held in registers
#define CAP (BLK * EPT)        // 4096: larger groups use global-memory fallback
#define CMAX 256               // max compacted candidates for exact-sort path

// ---------- reductions ----------

__device__ __forceinline__ void block_maxsum(float& m, float& s, float* redf, int tid) {
#pragma unroll
  for (int o = 32; o; o >>= 1) { m = fmaxf(m, __shfl_down(m, o)); s += __shfl_down(s, o); }
  __syncthreads();
  if ((tid & 63) == 0) { redf[tid >> 6] = m; redf[4 + (tid >> 6)] = s; }
  __syncthreads();
  m = fmaxf(fmaxf(redf[0], redf[1]), fmaxf(redf[2], redf[3]));
  s = redf[4] + redf[5] + redf[6] + redf[7];
}

__device__ __forceinline__ void block_sum_cnt(float& s, int& c, float* redf, int* redi, int tid) {
#pragma unroll
  for (int o = 32; o; o >>= 1) { s += __shfl_down(s, o); c += __shfl_down(c, o); }
  __syncthreads();
  if ((tid & 63) == 0) { redf[tid >> 6] = s; redi[tid >> 6] = c; }
  __syncthreads();
  s = redf[0] + redf[1] + redf[2] + redf[3];
  c = redi[0] + redi[1] + redi[2] + redi[3];
}

// ---------- kernel 1: boundary detect -> starts[0..B] ----------
// starts[g] = first index i with batch[i] >= g; starts[B] = N. Every entry
// in [0,B] is written exactly once (poisoned d_ws is fully initialized).

extern "C" __global__ void __launch_bounds__(256)
build_starts(const int* __restrict__ batch, int* __restrict__ starts,
             const int* __restrict__ pB, int N) {
  const int B = *pB;
  const int stride = gridDim.x * blockDim.x;
  for (int i = blockIdx.x * blockDim.x + threadIdx.x; i < N; i += stride) {
    const int b = batch[i];
    const int prev = (i == 0) ? -1 : batch[i - 1];
    for (int g = prev + 1; g <= b; ++g) starts[g] = i;   // covers empty groups too
    if (i == N - 1) {
      for (int g = b + 1; g <= B; ++g) starts[g] = N;    // trailing empty groups
    }
  }
}

// ---------- kernel 2: one block per group ----------
// Support bound: outputs sum to 1 => (0 - tau)+ <= 1 => tau >= -1 (shifted).
// So support subset of {x > gmax - 1}; compact those (~22 for Gaussian n=2048)
// and solve exactly by sorting the candidate prefix. Classical prefix property
// of the sparsemax condition makes the candidate-prefix evaluation identical
// to the reference's full-array evaluation.

extern "C" __global__ void __launch_bounds__(BLK)
sparsemax_groups(const float* __restrict__ x, const int* __restrict__ starts,
                 const int* __restrict__ pB, float* __restrict__ out, int N) {
  __shared__ float redf[8];
  __shared__ int   redi[4];
  __shared__ float cand[CMAX];
  __shared__ float sorted[CMAX];
  __shared__ int   s_cnt;
  __shared__ float s_tau;
  const int tid = threadIdx.x;
  const int B = *pB;

  for (int g = blockIdx.x; g < B; g += gridDim.x) {
    const int s = starts[g];
    const int e = starts[g + 1];
    const int n = e - s;
    if (n <= 0) continue;

    if (n <= CAP) {
      // ---- pass 1: global -> registers, fused max+sum ----
      float r[EPT];
      float gmax = -INFINITY, gsum = 0.0f;
#pragma unroll
      for (int j = 0; j < EPT; ++j) {
        const int i = tid + j * BLK;
        float v = -INFINITY;
        if (i < n) { v = x[s + i]; gmax = fmaxf(gmax, v); gsum += v; }
        r[j] = v;                      // padding = -inf: never passes > thr
      }
      block_maxsum(gmax, gsum, redf, tid);

      // ---- pass 2: compact candidates (x > gmax - 1) into LDS ----
      if (tid == 0) s_cnt = 0;
      __syncthreads();
      const float thr = gmax - 1.0f;
#pragma unroll
      for (int j = 0; j < EPT; ++j) {
        if (r[j] > thr) {
          const int p = atomicAdd(&s_cnt, 1);
          if (p < CMAX) cand[p] = r[j];
        }
      }
      __syncthreads();
      const int c = s_cnt;

      float tau;                        // shifted-space threshold
      if (c <= CMAX) {
        // exact: all-pairs rank sort (c ~ 22 typical, broadcast LDS reads)
        if (tid < c) {
          const float v = cand[tid];
          int rank = 0;
          for (int q = 0; q < c; ++q) {
            const float t = cand[q];
            rank += (t > v) || (t == v && q < tid);   // stable, unique ranks
          }
          sorted[rank] = v - gmax;      // shift to xs space (sorted[0] == 0)
        }
        __syncthreads();
        if (tid < 64) {
          if (c <= 64) {                // common case: wave-0 parallel solve
            const float sv = (tid < c) ? sorted[tid] : 0.0f;
            float cs = sv;
#pragma unroll
            for (int o = 1; o < 64; o <<= 1) {   // inclusive prefix scan
              const float t = __shfl_up(cs, o);
              if (tid >= o) cs += t;
            }
            const int flag = (tid < c) && (sv * (float)(tid + 1) > cs - 1.0f);
            const unsigned long long bal = __ballot(flag);  // nonzero: lane 0 true
            const int k = 63 - __clzll(bal);                // last true index
            const float csk = __shfl(cs, k);
            if (tid == 0) s_tau = (csk - 1.0f) / (float)(k + 1);
          } else if (tid == 0) {        // rare: serial over <=256 sorted
            float cs = 0.0f, tv = 0.0f;
            for (int j2 = 0; j2 < c; ++j2) {
              cs += sorted[j2];
              if (sorted[j2] * (float)(j2 + 1) > cs - 1.0f)
                tv = (cs - 1.0f) / (float)(j2 + 1);
            }
            s_tau = tv;
          }
        }
        __syncthreads();
        tau = s_tau;
      } else {
        // pathological (c > 256): Michelot on registers
        tau = (gsum - (float)n * gmax - 1.0f) / (float)n;
        int cnt = n;
        for (int it = 0; it < 64; ++it) {
          float bs = 0.0f; int bc = 0;
#pragma unroll
          for (int j = 0; j < EPT; ++j) {
            const float v = r[j] - gmax;        // -inf padding never > tau
            if (v > tau) { bs += v; bc++; }
          }
          block_sum_cnt(bs, bc, redf, redi, tid);
          if (bc == cnt || bc == 0) break;
          tau = (bs - 1.0f) / (float)bc;
          cnt = bc;
        }
      }

      // ---- pass 3: write output from registers ----
      const float sub = tau + gmax;             // unshifted threshold
#pragma unroll
      for (int j = 0; j < EPT; ++j) {
        const int i = tid + j * BLK;
        if (i < n) {
          const float v = r[j] - sub;
          out[s + i] = v > 0.0f ? v : 0.0f;
        }
      }
    } else {
      // ---- n > CAP fallback: global-memory Michelot (never hit in bench) ----
      float gmax = -INFINITY, gsum = 0.0f;
      for (int i = tid; i < n; i += BLK) { const float v = x[s + i]; gmax = fmaxf(gmax, v); gsum += v; }
      block_maxsum(gmax, gsum, redf, tid);

      float tau = (gsum - (float)n * gmax - 1.0f) / (float)n;
      int cnt = n;
      for (int it = 0; it < 64; ++it) {
        float bs = 0.0f; int bc = 0;
        for (int i = tid; i < n; i += BLK) {
          const float v = x[s + i] - gmax;
          if (v > tau) { bs += v; bc++; }
        }
        block_sum_cnt(bs, bc, redf, redi, tid);
        if (bc == cnt || bc == 0) break;
        tau = (bs - 1.0f) / (float)bc;
        cnt = bc;
      }
      const float sub = tau + gmax;
      for (int i = tid; i < n; i += BLK) {
        const float v = x[s + i] - sub;
        out[s + i] = v > 0.0f ? v : 0.0f;
      }
    }
  }
}

extern "C" void kernel_launch(void* const* d_in, const int* in_sizes, int n_in,
                              void* d_out, int out_size, void* d_ws, size_t ws_size,
                              hipStream_t stream) {
  const float* x     = (const float*)d_in[0];
  const int*   batch = (const int*)d_in[1];   // int32 on device (JAX x64 disabled)
  const int*   pB    = (const int*)d_in[2];
  float*       out   = (float*)d_out;
  const int N = in_sizes[0];

  int* starts = (int*)d_ws;                    // needs 4*(B+1) bytes of scratch

  const int g1 = (N + 255) / 256;
  build_starts<<<dim3(g1 > 16384 ? 16384 : g1), dim3(256), 0, stream>>>(batch, starts, pB, N);
  sparsemax_groups<<<dim3(4096), dim3(BLK), 0, stream>>>(x, starts, pB, out, N);
}

// Round 4
// 117.687 us; speedup vs baseline: 1.3142x; 1.0989x over previous
//
#include <hip/hip_runtime.h>

#define BLK 256
#define WPB 4                  // waves per block
#define RPT4 12                // float4 per lane -> 3072-element capacity per wave
#define CAPW (RPT4 * 64 * 4)   // 3072
#define CCAP 72                // per-wave candidate buffer (exact path needs c <= 64)

// ---------- wave-local reductions (no barriers, 64-lane) ----------

__device__ __forceinline__ float wave_max(float v) {
#pragma unroll
  for (int o = 32; o; o >>= 1) v = fmaxf(v, __shfl_xor(v, o));
  return v;
}
__device__ __forceinline__ float wave_sum(float v) {
#pragma unroll
  for (int o = 32; o; o >>= 1) v += __shfl_xor(v, o);
  return v;
}
__device__ __forceinline__ int wave_sum_i(int v) {
#pragma unroll
  for (int o = 32; o; o >>= 1) v += __shfl_xor(v, o);
  return v;
}

// ---------- kernel 1: boundary detect -> starts[0..B], int4-vectorized ----------

extern "C" __global__ void __launch_bounds__(256)
build_starts(const int* __restrict__ batch, int* __restrict__ starts,
             const int* __restrict__ pB, int N) {
  const int B = *pB;
  const long long tid = (long long)blockIdx.x * 256 + threadIdx.x;
  const long long i0 = tid * 8;
  if (i0 >= N) return;
  int v[8];
  if (i0 + 8 <= N) {
    const int4 a = *(const int4*)(batch + i0);
    const int4 b = *(const int4*)(batch + i0 + 4);
    v[0] = a.x; v[1] = a.y; v[2] = a.z; v[3] = a.w;
    v[4] = b.x; v[5] = b.y; v[6] = b.z; v[7] = b.w;
  } else {
#pragma unroll
    for (int t = 0; t < 8; ++t) v[t] = (i0 + t < N) ? batch[i0 + t] : 0;
  }
  int prev = (i0 == 0) ? -1 : batch[i0 - 1];   // L1-hit: same line as neighbor's load
#pragma unroll
  for (int t = 0; t < 8; ++t) {
    if (i0 + t >= N) break;
    const int cur = v[t];
    for (int g = prev + 1; g <= cur; ++g) starts[g] = (int)(i0 + t);  // ~B hits total
    prev = cur;
  }
  if (i0 + 8 >= N) {
    for (int g = prev + 1; g <= B; ++g) starts[g] = N;  // trailing empties
  }
}

// ---------- kernel 2: ONE WAVE PER GROUP, zero barriers ----------
// tau >= -1 bound (outputs sum to 1) => support subset of {x > gmax-1};
// compact (~4-25 cands) into per-wave LDS, exact rank-sort + shfl prefix
// scan + ballot solve. Register-resident data, float4 global traffic.

extern "C" __global__ void __launch_bounds__(BLK)
sparsemax_groups(const float* __restrict__ x, const int* __restrict__ starts,
                 const int* __restrict__ pB, float* __restrict__ out, int N) {
  __shared__ float cand[WPB][CCAP];
  __shared__ float sorted[WPB][CCAP];
  __shared__ int   cnt[WPB];
  const int lane = threadIdx.x & 63;
  const int w    = threadIdx.x >> 6;
  const int B = *pB;
  const int wstride = gridDim.x * WPB;

  for (int g = blockIdx.x * WPB + w; g < B; g += wstride) {
    const int s = starts[g];
    const int e = starts[g + 1];
    const int n = e - s;
    if (n <= 0) continue;
    const int a0 = s & ~3;               // 16B-aligned load base

    if (e - a0 <= CAPW) {
      // ---- pass 1: aligned float4 global -> registers, fused max ----
      float4 r[RPT4];
      float gmax = -INFINITY;
#pragma unroll
      for (int j = 0; j < RPT4; ++j) {
        const int idx = a0 + (j * 64 + lane) * 4;
        float4 v = make_float4(-INFINITY, -INFINITY, -INFINITY, -INFINITY);
        if (idx < e) {
          if (idx + 4 <= N) {
            v = *(const float4*)(x + idx);
          } else {                        // buffer tail (last group only)
            if (idx + 0 < N) v.x = x[idx + 0];
            if (idx + 1 < N) v.y = x[idx + 1];
            if (idx + 2 < N) v.z = x[idx + 2];
            if (idx + 3 < N) v.w = x[idx + 3];
          }
          if (idx + 0 < s || idx + 0 >= e) v.x = -INFINITY;  // mask other groups
          if (idx + 1 < s || idx + 1 >= e) v.y = -INFINITY;
          if (idx + 2 < s || idx + 2 >= e) v.z = -INFINITY;
          if (idx + 3 < s || idx + 3 >= e) v.w = -INFINITY;
        }
        r[j] = v;
        gmax = fmaxf(gmax, fmaxf(fmaxf(v.x, v.y), fmaxf(v.z, v.w)));
      }
      gmax = wave_max(gmax);

      // ---- pass 2: compact candidates (x > gmax-1) into per-wave LDS ----
      if (lane == 0) cnt[w] = 0;         // in-wave program order: safe, no barrier
      const float thr = gmax - 1.0f;
      float csum = 0.0f; int cm = 0;     // side products for fallback
#pragma unroll
      for (int j = 0; j < RPT4; ++j) {
        const float vv[4] = {r[j].x, r[j].y, r[j].z, r[j].w};
#pragma unroll
        for (int t = 0; t < 4; ++t) {
          if (vv[t] > thr) {
            const int p = atomicAdd(&cnt[w], 1);
            if (p < CCAP) cand[w][p] = vv[t];
            csum += vv[t] - gmax; cm++;
          }
        }
      }
      const int c = wave_sum_i(cm);      // total candidates (>=1: max elem)

      float tau;                          // shifted-space threshold
      if (c <= 64) {
        // exact: all-pairs rank sort (LDS broadcast reads) + shfl scan
        const float v = (lane < c) ? cand[w][lane] - gmax : 0.0f;
        int rank = 0;
        for (int q = 0; q < c; ++q) {
          const float t = cand[w][q] - gmax;
          rank += (t > v) || (t == v && q < lane);  // stable unique ranks
        }
        if (lane < c) sorted[w][rank] = v;          // sorted[0] == 0
        const float sv = (lane < c) ? sorted[w][lane] : 0.0f;
        float cs = sv;
#pragma unroll
        for (int o = 1; o < 64; o <<= 1) {          // inclusive prefix scan
          const float t = __shfl_up(cs, o);
          if (lane >= o) cs += t;
        }
        const int flag = (lane < c) && (sv * (float)(lane + 1) > cs - 1.0f);
        const unsigned long long bal = __ballot(flag);  // lane 0 always true
        const int k = 63 - __clzll(bal);                // support size - 1
        const float csk = __shfl(cs, k);
        tau = (csk - 1.0f) / (float)(k + 1);
      } else {
        // pathological: Michelot on registers, start from candidate set
        float bs = wave_sum(csum); int bc = c;
        tau = (bs - 1.0f) / (float)bc;
        for (int it = 0; it < 64; ++it) {
          float s2 = 0.0f; int c2 = 0;
#pragma unroll
          for (int j = 0; j < RPT4; ++j) {
            const float vv[4] = {r[j].x, r[j].y, r[j].z, r[j].w};
#pragma unroll
            for (int t = 0; t < 4; ++t) {
              const float vs = vv[t] - gmax;        // -inf never passes
              if (vs > tau) { s2 += vs; c2++; }
            }
          }
          s2 = wave_sum(s2); c2 = wave_sum_i(c2);
          if (c2 == bc || c2 == 0) break;
          tau = (s2 - 1.0f) / (float)c2; bc = c2;
        }
      }

      // ---- pass 3: store (vector interior, scalar boundary quads) ----
      const float sub = tau + gmax;
#pragma unroll
      for (int j = 0; j < RPT4; ++j) {
        const int idx = a0 + (j * 64 + lane) * 4;
        if (idx >= e) continue;
        if (idx >= s && idx + 4 <= e) {
          float4 o4;
          o4.x = fmaxf(r[j].x - sub, 0.0f);
          o4.y = fmaxf(r[j].y - sub, 0.0f);
          o4.z = fmaxf(r[j].z - sub, 0.0f);
          o4.w = fmaxf(r[j].w - sub, 0.0f);
          *(float4*)(out + idx) = o4;
        } else {
          const float vv[4] = {r[j].x, r[j].y, r[j].z, r[j].w};
#pragma unroll
          for (int t = 0; t < 4; ++t) {
            const int p = idx + t;
            if (p >= s && p < e) out[p] = fmaxf(vv[t] - sub, 0.0f);
          }
        }
      }
    } else {
      // ---- n > capacity fallback: wave-strided global Michelot ----
      float gmax = -INFINITY;
      for (int i = s + lane; i < e; i += 64) gmax = fmaxf(gmax, x[i]);
      gmax = wave_max(gmax);
      float bs = 0.0f; int bc = 0;
      for (int i = s + lane; i < e; i += 64) {
        const float vs = x[i] - gmax;
        if (vs > -1.0f) { bs += vs; bc++; }
      }
      bs = wave_sum(bs); bc = wave_sum_i(bc);
      float tau = (bs - 1.0f) / (float)bc;
      int cntS = bc;
      for (int it = 0; it < 64; ++it) {
        float s2 = 0.0f; int c2 = 0;
        for (int i = s + lane; i < e; i += 64) {
          const float vs = x[i] - gmax;
          if (vs > tau) { s2 += vs; c2++; }
        }
        s2 = wave_sum(s2); c2 = wave_sum_i(c2);
        if (c2 == cntS || c2 == 0) break;
        tau = (s2 - 1.0f) / (float)c2; cntS = c2;
      }
      const float sub = tau + gmax;
      for (int i = s + lane; i < e; i += 64) out[i] = fmaxf(x[i] - sub, 0.0f);
    }
  }
}

extern "C" void kernel_launch(void* const* d_in, const int* in_sizes, int n_in,
                              void* d_out, int out_size, void* d_ws, size_t ws_size,
                              hipStream_t stream) {
  const float* x     = (const float*)d_in[0];
  const int*   batch = (const int*)d_in[1];   // int32 on device (JAX x64 disabled)
  const int*   pB    = (const int*)d_in[2];
  float*       out   = (float*)d_out;
  const int N = in_sizes[0];

  int* starts = (int*)d_ws;                    // 4*(B+1) bytes of scratch

  const int g1 = (N + 2047) / 2048;            // 8 elems/thread, 256 threads
  build_starts<<<dim3(g1), dim3(256), 0, stream>>>(batch, starts, pB, N);
  // one wave per group: 1024 blocks x 4 waves covers B=4096; grid-strides beyond
  sparsemax_groups<<<dim3(1024), dim3(BLK), 0, stream>>>(x, starts, pB, out, N);
}

// Round 5
// 112.439 us; speedup vs baseline: 1.3756x; 1.0467x over previous
//
#include <hip/hip_runtime.h>

#define BLK 256
#define QPT 3                   // float4 per thread -> 3072-element capacity per block
#define CAPB (QPT * BLK * 4)    // 3072
#define CCAP 320                // candidate buffer: c<=64 exact; <=CCAP wave-Michelot; else block Michelot

// ---------- wave-local reductions (64-lane) ----------

__device__ __forceinline__ float wave_max(float v) {
#pragma unroll
  for (int o = 32; o; o >>= 1) v = fmaxf(v, __shfl_xor(v, o));
  return v;
}
__device__ __forceinline__ float wave_sum(float v) {
#pragma unroll
  for (int o = 32; o; o >>= 1) v += __shfl_xor(v, o);
  return v;
}
__device__ __forceinline__ int wave_sum_i(int v) {
#pragma unroll
  for (int o = 32; o; o >>= 1) v += __shfl_xor(v, o);
  return v;
}

__device__ __forceinline__ void block_sum_cnt(float& s, int& c, float* redf, int* redi, int tid) {
  s = wave_sum(s); c = wave_sum_i(c);
  __syncthreads();
  if ((tid & 63) == 0) { redf[tid >> 6] = s; redi[tid >> 6] = c; }
  __syncthreads();
  s = redf[0] + redf[1] + redf[2] + redf[3];
  c = redi[0] + redi[1] + redi[2] + redi[3];
}

// ---------- kernel 1: boundary detect -> starts[0..B], int4-vectorized ----------

extern "C" __global__ void __launch_bounds__(256)
build_starts(const int* __restrict__ batch, int* __restrict__ starts,
             const int* __restrict__ pB, int N) {
  const int B = *pB;
  const long long tid = (long long)blockIdx.x * 256 + threadIdx.x;
  const long long i0 = tid * 8;
  if (i0 >= N) return;
  int v[8];
  if (i0 + 8 <= N) {
    const int4 a = *(const int4*)(batch + i0);
    const int4 b = *(const int4*)(batch + i0 + 4);
    v[0] = a.x; v[1] = a.y; v[2] = a.z; v[3] = a.w;
    v[4] = b.x; v[5] = b.y; v[6] = b.z; v[7] = b.w;
  } else {
#pragma unroll
    for (int t = 0; t < 8; ++t) v[t] = (i0 + t < N) ? batch[i0 + t] : 0;
  }
  int prev = (i0 == 0) ? -1 : batch[i0 - 1];   // same cacheline as neighbor: L1 hit
#pragma unroll
  for (int t = 0; t < 8; ++t) {
    if (i0 + t >= N) break;
    const int cur = v[t];
    for (int g = prev + 1; g <= cur; ++g) starts[g] = (int)(i0 + t);
    prev = cur;
  }
  if (i0 + 8 >= N) {
    for (int g = prev + 1; g <= B; ++g) starts[g] = N;
  }
}

// ---------- kernel 2: one BLOCK (4 waves) per group, 3 barriers ----------
// tau >= -1 bound (outputs sum to 1) => support subset of {x > gmax-1};
// ballot-compact (~25 cands for Gaussian n=2048) into LDS, exact rank-sort
// + shfl prefix-scan + ballot solve on wave 0. Payload stays in registers.

extern "C" __global__ void __launch_bounds__(BLK)
sparsemax_groups(const float* __restrict__ x, const int* __restrict__ starts,
                 const int* __restrict__ pB, float* __restrict__ out, int N) {
  __shared__ float redf[4];
  __shared__ int   redi[4];
  __shared__ float cand[CCAP];
  __shared__ float sorted[64];
  __shared__ int   s_cnt;
  __shared__ float s_csum;
  __shared__ float s_tau;
  const int tid  = threadIdx.x;
  const int lane = tid & 63;
  const int w    = tid >> 6;
  const int B = *pB;

  for (int g = blockIdx.x; g < B; g += gridDim.x) {
    const int s = starts[g];
    const int e = starts[g + 1];
    const int n = e - s;
    if (n <= 0) continue;
    const int a0 = s & ~3;               // 16B-aligned load base

    if (e - a0 <= CAPB) {
      // ---- phase 1: aligned float4 global -> registers, fused max ----
      float4 r[QPT];
      float lmax = -INFINITY;
#pragma unroll
      for (int j = 0; j < QPT; ++j) {
        const int idx = a0 + (j * BLK + tid) * 4;
        float4 v = make_float4(-INFINITY, -INFINITY, -INFINITY, -INFINITY);
        if (idx < e) {
          if (idx + 4 <= N) {
            v = *(const float4*)(x + idx);
          } else {                        // buffer tail (last group only)
            if (idx + 0 < N) v.x = x[idx + 0];
            if (idx + 1 < N) v.y = x[idx + 1];
            if (idx + 2 < N) v.z = x[idx + 2];
            if (idx + 3 < N) v.w = x[idx + 3];
          }
          if (idx + 0 < s || idx + 0 >= e) v.x = -INFINITY;  // mask other groups
          if (idx + 1 < s || idx + 1 >= e) v.y = -INFINITY;
          if (idx + 2 < s || idx + 2 >= e) v.z = -INFINITY;
          if (idx + 3 < s || idx + 3 >= e) v.w = -INFINITY;
        }
        r[j] = v;
        lmax = fmaxf(lmax, fmaxf(fmaxf(v.x, v.y), fmaxf(v.z, v.w)));
      }
      lmax = wave_max(lmax);
      if (lane == 0) redf[w] = lmax;
      if (tid == 0) { s_cnt = 0; s_csum = 0.0f; }
      __syncthreads();                   // barrier 1
      const float gmax = fmaxf(fmaxf(redf[0], redf[1]), fmaxf(redf[2], redf[3]));
      const float thr = gmax - 1.0f;

      // ---- phase 2: ballot compaction, ONE LDS atomic per wave per component ----
      float wsum = 0.0f;                 // this lane's candidate sum (shifted)
#pragma unroll
      for (int j = 0; j < QPT; ++j) {
        const float vv[4] = {r[j].x, r[j].y, r[j].z, r[j].w};
#pragma unroll
        for (int t = 0; t < 4; ++t) {
          const bool p = vv[t] > thr;
          const unsigned long long bal = __ballot(p);
          if (bal) {
            int base = 0;
            if (lane == 0) base = atomicAdd(&s_cnt, __popcll(bal));
            base = __shfl(base, 0);
            if (p) {
              const int off = base + __popcll(bal & ((1ull << lane) - 1ull));
              if (off < CCAP) cand[off] = vv[t];
              wsum += vv[t] - gmax;
            }
          }
        }
      }
      wsum = wave_sum(wsum);
      if (lane == 0) atomicAdd(&s_csum, wsum);
      __syncthreads();                   // barrier 2
      const int c = s_cnt;               // >= 1 (max element always passes)

      if (c <= 64) {
        if (w == 0) {                    // exact solve on wave 0
          const float v = (lane < c) ? cand[lane] - gmax : 0.0f;
          int rank = 0;
          for (int q = 0; q < c; ++q) {
            const float t = cand[q] - gmax;
            rank += (t > v) || (t == v && q < lane);  // unique ranks
          }
          if (lane < c) sorted[rank] = v;             // sorted[0] == 0
          const float sv = (lane < c) ? sorted[lane] : 0.0f;
          float cs = sv;
#pragma unroll
          for (int o = 1; o < 64; o <<= 1) {          // inclusive prefix scan
            const float t2 = __shfl_up(cs, o);
            if (lane >= o) cs += t2;
          }
          const int flag = (lane < c) && (sv * (float)(lane + 1) > cs - 1.0f);
          const unsigned long long bal2 = __ballot(flag);  // lane 0 always true
          const int k = 63 - __clzll(bal2);                // support size - 1
          const float csk = __shfl(cs, k);
          if (lane == 0) s_tau = (csk - 1.0f) / (float)(k + 1);
        }
      } else if (c <= CCAP) {
        if (w == 0) {                    // wave-0 Michelot over LDS candidates
          float tau = (s_csum - 1.0f) / (float)c;
          int cnt = c;
          for (int it = 0; it < 64; ++it) {
            float s2 = 0.0f; int c2 = 0;
            for (int q = lane; q < c; q += 64) {
              const float vs = cand[q] - gmax;
              if (vs > tau) { s2 += vs; c2++; }
            }
            s2 = wave_sum(s2); c2 = wave_sum_i(c2);
            if (c2 == cnt || c2 == 0) break;
            tau = (s2 - 1.0f) / (float)c2; cnt = c2;
          }
          if (lane == 0) s_tau = tau;
        }
      } else {
        // block-uniform pathological path: Michelot on registers (has barriers)
        float tau = (s_csum - 1.0f) / (float)c;
        int cnt = c;
        for (int it = 0; it < 64; ++it) {
          float s2 = 0.0f; int c2 = 0;
#pragma unroll
          for (int j = 0; j < QPT; ++j) {
            const float vv[4] = {r[j].x, r[j].y, r[j].z, r[j].w};
#pragma unroll
            for (int t = 0; t < 4; ++t) {
              const float vs = vv[t] - gmax;            // -inf never passes
              if (vs > tau) { s2 += vs; c2++; }
            }
          }
          block_sum_cnt(s2, c2, redf, redi, tid);
          if (c2 == cnt || c2 == 0) break;
          tau = (s2 - 1.0f) / (float)c2; cnt = c2;
        }
        if (tid == 0) s_tau = tau;
      }
      __syncthreads();                   // barrier 3
      const float sub = s_tau + gmax;    // unshifted threshold

      // ---- phase 3: store (vector interior, scalar boundary quads) ----
#pragma unroll
      for (int j = 0; j < QPT; ++j) {
        const int idx = a0 + (j * BLK + tid) * 4;
        if (idx >= e) continue;
        if (idx >= s && idx + 4 <= e) {
          float4 o4;
          o4.x = fmaxf(r[j].x - sub, 0.0f);
          o4.y = fmaxf(r[j].y - sub, 0.0f);
          o4.z = fmaxf(r[j].z - sub, 0.0f);
          o4.w = fmaxf(r[j].w - sub, 0.0f);
          *(float4*)(out + idx) = o4;
        } else {
          const float vv[4] = {r[j].x, r[j].y, r[j].z, r[j].w};
#pragma unroll
          for (int t = 0; t < 4; ++t) {
            const int p2 = idx + t;
            if (p2 >= s && p2 < e) out[p2] = fmaxf(vv[t] - sub, 0.0f);
          }
        }
      }
    } else {
      // ---- n > capacity fallback: block-strided global Michelot ----
      float gmax = -INFINITY;
      for (int i = s + tid; i < e; i += BLK) gmax = fmaxf(gmax, x[i]);
      gmax = wave_max(gmax);
      if (lane == 0) redf[w] = gmax;
      __syncthreads();
      gmax = fmaxf(fmaxf(redf[0], redf[1]), fmaxf(redf[2], redf[3]));
      float bs = 0.0f; int bc = 0;
      for (int i = s + tid; i < e; i += BLK) {
        const float vs = x[i] - gmax;
        if (vs > -1.0f) { bs += vs; bc++; }
      }
      block_sum_cnt(bs, bc, redf, redi, tid);
      float tau = (bs - 1.0f) / (float)bc;
      int cntS = bc;
      for (int it = 0; it < 64; ++it) {
        float s2 = 0.0f; int c2 = 0;
        for (int i = s + tid; i < e; i += BLK) {
          const float vs = x[i] - gmax;
          if (vs > tau) { s2 += vs; c2++; }
        }
        block_sum_cnt(s2, c2, redf, redi, tid);
        if (c2 == cntS || c2 == 0) break;
        tau = (s2 - 1.0f) / (float)c2; cntS = c2;
      }
      const float sub = tau + gmax;
      for (int i = s + tid; i < e; i += BLK) out[i] = fmaxf(x[i] - sub, 0.0f);
    }
  }
}

extern "C" void kernel_launch(void* const* d_in, const int* in_sizes, int n_in,
                              void* d_out, int out_size, void* d_ws, size_t ws_size,
                              hipStream_t stream) {
  const float* x     = (const float*)d_in[0];
  const int*   batch = (const int*)d_in[1];   // int32 on device (JAX x64 disabled)
  const int*   pB    = (const int*)d_in[2];
  float*       out   = (float*)d_out;
  const int N = in_sizes[0];

  int* starts = (int*)d_ws;                    // 4*(B+1) bytes of scratch

  const int g1 = (N + 2047) / 2048;            // 8 elems/thread, 256 threads
  build_starts<<<dim3(g1), dim3(256), 0, stream>>>(batch, starts, pB, N);
  // one block (4 waves) per group; grid-strides if B > 4096
  sparsemax_groups<<<dim3(4096), dim3(BLK), 0, stream>>>(x, starts, pB, out, N);
}